// Round 4
// baseline (87.088 us; speedup 1.0000x reference)
//
#include <hip/hip_runtime.h>

#define MPB 4   // molecules (one wave each) per 256-thread block

__device__ __forceinline__ float readlane_f(float v, int lane) {
    return __builtin_bit_cast(float,
        __builtin_amdgcn_readlane(__builtin_bit_cast(int, v), lane));
}

// One wave per molecule. Lane t = atom t. No LDS, no barriers:
// cross-lane broadcast of atom j via v_readlane (j is wave-uniform).
__global__ __launch_bounds__(256) void mol_kernel(
    const float* __restrict__ coords,      // [N,3] flat
    const int*   __restrict__ species,     // [N]
    const int*   __restrict__ num_atoms,   // [B]
    const float* __restrict__ radii,       // [95]
    float* __restrict__ penv,              // [B] per-molecule penalty (ws)
    float* __restrict__ out,               // [1 + 3N]
    int Bm) {
    const int w  = threadIdx.x >> 6;
    const int tw = threadIdx.x & 63;
    const int m  = blockIdx.x * MPB + w;
    if (m >= Bm) return;

    // Per-wave exclusive prefix sum of num_atoms -> molecule start offset.
    // num_atoms is 16 KB -> L1/L2 resident; <=65 coalesced iterations.
    int acc = 0;
    for (int i = tw; i < m; i += 64) acc += num_atoms[i];
    #pragma unroll
    for (int d = 32; d > 0; d >>= 1) acc += __shfl_down(acc, d);
    const int off = __shfl(acc, 0);
    const int n   = num_atoms[m];

    // Per-lane direct load: lane t owns atom t (wave covers 768 contiguous B).
    float x = 0.f, y = 0.f, z = 0.f, r = 0.f;
    if (tw < n) {
        const float* cp = coords + 3 * (size_t)(off + tw);
        x = cp[0]; y = cp[1]; z = cp[2];
        r = radii[species[off + tw]];
    }

    // Segment mean via wave reduce (inactive lanes contribute 0).
    float sx = x, sy = y, sz = z;
    #pragma unroll
    for (int d = 32; d > 0; d >>= 1) {
        sx += __shfl_down(sx, d);
        sy += __shfl_down(sy, d);
        sz += __shfl_down(sz, d);
    }
    const float invn = 1.0f / (float)n;
    const float mx = __shfl(sx, 0) * invn;
    const float my = __shfl(sy, 0) * invn;
    const float mz = __shfl(sz, 0) * invn;

    // Pairwise repulsion: broadcast atom j from lane j's registers.
    float pen = 0.0f;
    const bool act = (tw < n);
    #pragma unroll 4
    for (int j = 0; j < n; ++j) {
        float ax = readlane_f(x, j);
        float ay = readlane_f(y, j);
        float az = readlane_f(z, j);
        float ar = readlane_f(r, j);
        float dx = x - ax, dy = y - ay, dz = z - az;
        float dist = sqrtf(dx * dx + dy * dy + dz * dz + 1e-8f);
        float v = (r + ar) * 0.8f - dist;
        pen += (act && j != tw && v > 0.0f) ? v * v : 0.0f;
    }
    #pragma unroll
    for (int d = 32; d > 0; d >>= 1) pen += __shfl_down(pen, d);
    if (tw == 0) penv[m] = (n > 1) ? pen * invn : 0.0f;

    // Centered write straight from registers.
    if (act) {
        float* op = out + 1 + 3 * (size_t)(off + tw);
        op[0] = x - mx;
        op[1] = y - my;
        op[2] = z - mz;
    }
}

// Sum per-molecule penalties -> out[0] = sum / B.
__global__ void reduce_kernel(const float4* __restrict__ pv4, int n4,
                              const float* __restrict__ tail, int rem,
                              float* __restrict__ out, float invB) {
    __shared__ float sdata[4];
    int t = threadIdx.x;
    float s = 0.f;
    for (int i = t; i < n4; i += 256) {
        float4 v = pv4[i];
        s += v.x + v.y + v.z + v.w;
    }
    if (t < rem) s += tail[t];
    #pragma unroll
    for (int d = 32; d > 0; d >>= 1) s += __shfl_down(s, d);
    if ((t & 63) == 0) sdata[t >> 6] = s;
    __syncthreads();
    if (t == 0) out[0] = (sdata[0] + sdata[1] + sdata[2] + sdata[3]) * invB;
}

extern "C" void kernel_launch(void* const* d_in, const int* in_sizes, int n_in,
                              void* d_out, int out_size, void* d_ws, size_t ws_size,
                              hipStream_t stream) {
    const float* cart_coords = (const float*)d_in[0];
    const int*   species     = (const int*)d_in[1];
    // d_in[2] = batch_indices (unused: offsets derived from num_atoms)
    const int*   num_atoms   = (const int*)d_in[3];
    const float* radii_table = (const float*)d_in[4];

    const int Bm = in_sizes[3];

    float* penv = (float*)d_ws;   // B floats (16B-aligned base)
    float* out  = (float*)d_out;

    mol_kernel<<<(Bm + MPB - 1) / MPB, 256, 0, stream>>>(
        cart_coords, species, num_atoms, radii_table, penv, out, Bm);

    const int n4  = Bm / 4;
    const int rem = Bm - 4 * n4;
    reduce_kernel<<<1, 256, 0, stream>>>((const float4*)penv, n4,
                                         penv + 4 * n4, rem, out, 1.0f / (float)Bm);
}

// Round 5
// 85.903 us; speedup vs baseline: 1.0138x; 1.0138x over previous
//
#include <hip/hip_runtime.h>

#define MPB 4   // molecules (one wave each) per 256-thread block

__device__ __forceinline__ float readlane_f(float v, int lane) {
    return __builtin_bit_cast(float,
        __builtin_amdgcn_readlane(__builtin_bit_cast(int, v), lane));
}

// Kernel 1: molecule start offsets from sorted batch_indices (boundary detect).
__global__ void offsets_kernel(const int* __restrict__ batch_indices, int N,
                               int* __restrict__ offsets) {
    int i = blockIdx.x * blockDim.x + threadIdx.x;
    if (i < N) {
        int b = batch_indices[i];
        if (i == 0 || batch_indices[i - 1] != b) offsets[b] = i;
    }
}

// Kernel 2: one wave per molecule. Lane t = atom t. No LDS, no barriers:
// atom j is broadcast from lane j's registers via v_readlane (j wave-uniform).
__global__ __launch_bounds__(256) void mol_kernel(
    const float* __restrict__ coords,      // [N,3] flat
    const int*   __restrict__ species,     // [N]
    const int*   __restrict__ num_atoms,   // [B]
    const float* __restrict__ radii,       // [95]
    const int*   __restrict__ offsets,     // [B] (ws)
    float* __restrict__ penv,              // [B] per-molecule penalty (ws)
    float* __restrict__ out,               // [1 + 3N]
    int Bm) {
    const int w  = threadIdx.x >> 6;
    const int tw = threadIdx.x & 63;
    const int m  = blockIdx.x * MPB + w;
    if (m >= Bm) return;

    const int n   = num_atoms[m];
    const int off = offsets[m];

    // Per-lane direct load: lane t owns atom t (wave covers 768 contiguous B).
    float x = 0.f, y = 0.f, z = 0.f, r = 0.f;
    const bool act = (tw < n);
    if (act) {
        const float* cp = coords + 3 * (size_t)(off + tw);
        x = cp[0]; y = cp[1]; z = cp[2];
        r = radii[species[off + tw]];
    }

    // Segment mean via wave reduce (inactive lanes contribute 0).
    float sx = x, sy = y, sz = z;
    #pragma unroll
    for (int d = 32; d > 0; d >>= 1) {
        sx += __shfl_down(sx, d);
        sy += __shfl_down(sy, d);
        sz += __shfl_down(sz, d);
    }
    const float invn = 1.0f / (float)n;
    const float mx = __shfl(sx, 0) * invn;
    const float my = __shfl(sy, 0) * invn;
    const float mz = __shfl(sz, 0) * invn;

    // Pairwise repulsion: broadcast atom j from lane j's registers.
    float pen = 0.0f;
    if (act) {
        #pragma unroll 4
        for (int j = 0; j < n; ++j) {
            float ax = readlane_f(x, j);
            float ay = readlane_f(y, j);
            float az = readlane_f(z, j);
            float ar = readlane_f(r, j);
            float dx = x - ax, dy = y - ay, dz = z - az;
            float dist = sqrtf(dx * dx + dy * dy + dz * dz + 1e-8f);
            float v = (r + ar) * 0.8f - dist;
            pen += (j != tw && v > 0.0f) ? v * v : 0.0f;
        }
    }
    #pragma unroll
    for (int d = 32; d > 0; d >>= 1) pen += __shfl_down(pen, d);
    if (tw == 0) penv[m] = (n > 1) ? pen * invn : 0.0f;

    // Centered write straight from registers (contiguous 768 B/wave region).
    if (act) {
        float* op = out + 1 + 3 * (size_t)(off + tw);
        op[0] = x - mx;
        op[1] = y - my;
        op[2] = z - mz;
    }
}

// Kernel 3: sum per-molecule penalties -> out[0] = sum / B.
__global__ void reduce_kernel(const float4* __restrict__ pv4, int n4,
                              const float* __restrict__ tail, int rem,
                              float* __restrict__ out, float invB) {
    __shared__ float sdata[4];
    int t = threadIdx.x;
    float s = 0.f;
    for (int i = t; i < n4; i += 256) {
        float4 v = pv4[i];
        s += v.x + v.y + v.z + v.w;
    }
    if (t < rem) s += tail[t];
    #pragma unroll
    for (int d = 32; d > 0; d >>= 1) s += __shfl_down(s, d);
    if ((t & 63) == 0) sdata[t >> 6] = s;
    __syncthreads();
    if (t == 0) out[0] = (sdata[0] + sdata[1] + sdata[2] + sdata[3]) * invB;
}

extern "C" void kernel_launch(void* const* d_in, const int* in_sizes, int n_in,
                              void* d_out, int out_size, void* d_ws, size_t ws_size,
                              hipStream_t stream) {
    const float* cart_coords   = (const float*)d_in[0];
    const int*   species       = (const int*)d_in[1];
    const int*   batch_indices = (const int*)d_in[2];
    const int*   num_atoms     = (const int*)d_in[3];
    const float* radii_table   = (const float*)d_in[4];

    const int N  = in_sizes[0] / 3;   // cart_coords is [N,3]
    const int Bm = in_sizes[3];       // num_atoms is [B]

    int*   offsets = (int*)d_ws;                 // B ints
    float* penv    = (float*)d_ws + Bm;          // B floats
    float* out     = (float*)d_out;

    offsets_kernel<<<(N + 255) / 256, 256, 0, stream>>>(batch_indices, N, offsets);
    mol_kernel<<<(Bm + MPB - 1) / MPB, 256, 0, stream>>>(
        cart_coords, species, num_atoms, radii_table, offsets, penv, out, Bm);

    const int n4  = Bm / 4;
    const int rem = Bm - 4 * n4;
    reduce_kernel<<<1, 256, 0, stream>>>((const float4*)penv, n4,
                                         penv + 4 * n4, rem, out, 1.0f / (float)Bm);
}

// Round 6
// 81.907 us; speedup vs baseline: 1.0633x; 1.0488x over previous
//
#include <hip/hip_runtime.h>

#define NMAX 64
#define MPB 4   // molecules (one wave each) per 256-thread block

// Kernel 1: molecule start offsets from sorted batch_indices (boundary detect).
__global__ void offsets_kernel(const int* __restrict__ batch_indices, int N,
                               int* __restrict__ offsets) {
    int i = blockIdx.x * blockDim.x + threadIdx.x;
    if (i < N) {
        int b = batch_indices[i];
        if (i == 0 || batch_indices[i - 1] != b) offsets[b] = i;
    }
}

// Kernel 2: one wave per molecule, MPB waves per block. Lane t = atom t.
// s4[w] is wave-private (written and read only by wave w) -> NO barriers:
// same-wave LDS RAW is ordered by compiler-inserted lgkmcnt waits.
__global__ __launch_bounds__(64 * MPB) void mol_kernel(
    const float* __restrict__ coords,      // [N,3] flat
    const int*   __restrict__ species,     // [N]
    const int*   __restrict__ num_atoms,   // [B]
    const float* __restrict__ radii,       // [95]
    const int*   __restrict__ offsets,     // [B] (ws)
    float* __restrict__ penv,              // [B] per-molecule penalty (ws)
    float* __restrict__ out,               // [1 + 3N]
    int Bm) {
    const int w  = threadIdx.x >> 6;
    const int tw = threadIdx.x & 63;
    const int m  = blockIdx.x * MPB + w;

    __shared__ float4 s4[MPB][NMAX];       // {x, y, z, r} per atom, wave-private slice

    if (m >= Bm) return;                   // safe: no cross-wave LDS sharing

    const int n   = num_atoms[m];
    const int off = offsets[m];

    // Per-lane direct load: lane t owns atom t (wave covers 768 contiguous B).
    float x = 0.f, y = 0.f, z = 0.f, r = 0.f;
    const bool act = (tw < n);
    if (act) {
        const float* cp = coords + 3 * (size_t)(off + tw);
        x = cp[0]; y = cp[1]; z = cp[2];
        r = radii[species[off + tw]];
    }
    s4[w][tw] = make_float4(x, y, z, r);   // one ds_write_b128 per lane

    // Segment mean via wave reduce (inactive lanes contribute 0).
    float sx = x, sy = y, sz = z;
    #pragma unroll
    for (int d = 32; d > 0; d >>= 1) {
        sx += __shfl_down(sx, d);
        sy += __shfl_down(sy, d);
        sz += __shfl_down(sz, d);
    }
    const float invn = 1.0f / (float)n;
    const float mx = __shfl(sx, 0) * invn;
    const float my = __shfl(sy, 0) * invn;
    const float mz = __shfl(sz, 0) * invn;

    // Pairwise repulsion: one broadcast ds_read_b128 per j (pipelined 4-deep).
    float pen = 0.0f;
    if (act) {
        #pragma unroll 4
        for (int j = 0; j < n; ++j) {
            float4 aj = s4[w][j];
            float dx = x - aj.x;
            float dy = y - aj.y;
            float dz = z - aj.z;
            float dist = sqrtf(dx * dx + dy * dy + dz * dz + 1e-8f);
            float v = (r + aj.w) * 0.8f - dist;
            pen += (j != tw && v > 0.0f) ? v * v : 0.0f;
        }
    }
    #pragma unroll
    for (int d = 32; d > 0; d >>= 1) pen += __shfl_down(pen, d);
    if (tw == 0) penv[m] = (n > 1) ? pen * invn : 0.0f;

    // Centered write straight from registers (contiguous 768 B/wave region).
    if (act) {
        float* op = out + 1 + 3 * (size_t)(off + tw);
        op[0] = x - mx;
        op[1] = y - my;
        op[2] = z - mz;
    }
}

// Kernel 3: sum per-molecule penalties -> out[0] = sum / B. 1024 threads so
// the load phase is ~1 float4 per lane instead of a 17-deep serial loop.
__global__ __launch_bounds__(1024) void reduce_kernel(
    const float4* __restrict__ pv4, int n4,
    const float* __restrict__ tail, int rem,
    float* __restrict__ out, float invB) {
    __shared__ float sdata[16];
    int t = threadIdx.x;
    float s = 0.f;
    for (int i = t; i < n4; i += 1024) {
        float4 v = pv4[i];
        s += v.x + v.y + v.z + v.w;
    }
    if (t < rem) s += tail[t];
    #pragma unroll
    for (int d = 32; d > 0; d >>= 1) s += __shfl_down(s, d);
    if ((t & 63) == 0) sdata[t >> 6] = s;
    __syncthreads();
    if (t == 0) {
        float tot = 0.f;
        #pragma unroll
        for (int i = 0; i < 16; ++i) tot += sdata[i];
        out[0] = tot * invB;
    }
}

extern "C" void kernel_launch(void* const* d_in, const int* in_sizes, int n_in,
                              void* d_out, int out_size, void* d_ws, size_t ws_size,
                              hipStream_t stream) {
    const float* cart_coords   = (const float*)d_in[0];
    const int*   species       = (const int*)d_in[1];
    const int*   batch_indices = (const int*)d_in[2];
    const int*   num_atoms     = (const int*)d_in[3];
    const float* radii_table   = (const float*)d_in[4];

    const int N  = in_sizes[0] / 3;   // cart_coords is [N,3]
    const int Bm = in_sizes[3];       // num_atoms is [B]

    int*   offsets = (int*)d_ws;                 // B ints
    float* penv    = (float*)d_ws + Bm;          // B floats (16B-aligned for Bm%4==0)
    float* out     = (float*)d_out;

    offsets_kernel<<<(N + 255) / 256, 256, 0, stream>>>(batch_indices, N, offsets);
    mol_kernel<<<(Bm + MPB - 1) / MPB, 64 * MPB, 0, stream>>>(
        cart_coords, species, num_atoms, radii_table, offsets, penv, out, Bm);

    const int n4  = Bm / 4;
    const int rem = Bm - 4 * n4;
    reduce_kernel<<<1, 1024, 0, stream>>>((const float4*)penv, n4,
                                          penv + 4 * n4, rem, out, 1.0f / (float)Bm);
}

// Round 7
// 78.791 us; speedup vs baseline: 1.1053x; 1.0395x over previous
//
#include <hip/hip_runtime.h>

#define NMAX 64
#define MPB 4   // molecules (one wave each) per 256-thread block

// One wave per molecule, MPB waves per block. Lane t = atom t.
// Offsets are derived in-kernel: block-cooperative prefix sum of
// num_atoms[0..base_m) (16 KB, L1/L2-hot) -> no separate offsets kernel.
__global__ __launch_bounds__(256) void mol_kernel(
    const float* __restrict__ coords,      // [N,3] flat
    const int*   __restrict__ species,     // [N]
    const int*   __restrict__ num_atoms,   // [B]
    const float* __restrict__ radii,       // [95]
    float* __restrict__ penv,              // [B] per-molecule penalty (ws)
    float* __restrict__ out,               // [1 + 3N]
    int Bm) {
    const int w      = threadIdx.x >> 6;
    const int tw     = threadIdx.x & 63;
    const int t      = threadIdx.x;
    const int base_m = blockIdx.x * MPB;
    const int m      = base_m + w;

    __shared__ float4 s4[MPB][NMAX];   // {x,y,z,r} per atom, wave-private slice
    __shared__ int    ssum[MPB];

    // Block-cooperative exclusive prefix: sum num_atoms[0..base_m).
    // <=17 coalesced strided loads per thread (table is hot in L1/L2).
    int acc = 0;
    for (int i = t; i < base_m; i += 256) acc += num_atoms[i];
    #pragma unroll
    for (int d = 32; d > 0; d >>= 1) acc += __shfl_down(acc, d);
    if (tw == 0) ssum[w] = acc;
    __syncthreads();                   // all waves reach this (no early return above)
    const int block_base = ssum[0] + ssum[1] + ssum[2] + ssum[3];

    if (m >= Bm) return;
    const int n = num_atoms[m];
    int off = block_base;
    for (int i = base_m; i < m; ++i) off += num_atoms[i];   // <=3 wave-uniform scalar loads

    // Per-lane direct load: lane t owns atom t (wave covers 768 contiguous B).
    float x = 0.f, y = 0.f, z = 0.f, r = 0.f;
    const bool act = (tw < n);
    if (act) {
        const float* cp = coords + 3 * (size_t)(off + tw);
        x = cp[0]; y = cp[1]; z = cp[2];
        r = radii[species[off + tw]];
    }
    s4[w][tw] = make_float4(x, y, z, r);   // wave-private: no barrier needed

    // Segment mean via wave reduce (inactive lanes contribute 0).
    float sx = x, sy = y, sz = z;
    #pragma unroll
    for (int d = 32; d > 0; d >>= 1) {
        sx += __shfl_down(sx, d);
        sy += __shfl_down(sy, d);
        sz += __shfl_down(sz, d);
    }
    const float invn = 1.0f / (float)n;
    const float mx = __shfl(sx, 0) * invn;
    const float my = __shfl(sy, 0) * invn;
    const float mz = __shfl(sz, 0) * invn;

    // Pairwise repulsion: one broadcast ds_read_b128 per j (pipelined 4-deep).
    float pen = 0.0f;
    if (act) {
        #pragma unroll 4
        for (int j = 0; j < n; ++j) {
            float4 aj = s4[w][j];
            float dx = x - aj.x;
            float dy = y - aj.y;
            float dz = z - aj.z;
            float dist = sqrtf(dx * dx + dy * dy + dz * dz + 1e-8f);
            float v = (r + aj.w) * 0.8f - dist;
            pen += (j != tw && v > 0.0f) ? v * v : 0.0f;
        }
    }
    #pragma unroll
    for (int d = 32; d > 0; d >>= 1) pen += __shfl_down(pen, d);
    if (tw == 0) penv[m] = (n > 1) ? pen * invn : 0.0f;

    // Centered write straight from registers (contiguous 768 B/wave region).
    if (act) {
        float* op = out + 1 + 3 * (size_t)(off + tw);
        op[0] = x - mx;
        op[1] = y - my;
        op[2] = z - mz;
    }
}

// Sum per-molecule penalties -> out[0] = sum / B.
__global__ __launch_bounds__(1024) void reduce_kernel(
    const float4* __restrict__ pv4, int n4,
    const float* __restrict__ tail, int rem,
    float* __restrict__ out, float invB) {
    __shared__ float sdata[16];
    int t = threadIdx.x;
    float s = 0.f;
    for (int i = t; i < n4; i += 1024) {
        float4 v = pv4[i];
        s += v.x + v.y + v.z + v.w;
    }
    if (t < rem) s += tail[t];
    #pragma unroll
    for (int d = 32; d > 0; d >>= 1) s += __shfl_down(s, d);
    if ((t & 63) == 0) sdata[t >> 6] = s;
    __syncthreads();
    if (t == 0) {
        float tot = 0.f;
        #pragma unroll
        for (int i = 0; i < 16; ++i) tot += sdata[i];
        out[0] = tot * invB;
    }
}

extern "C" void kernel_launch(void* const* d_in, const int* in_sizes, int n_in,
                              void* d_out, int out_size, void* d_ws, size_t ws_size,
                              hipStream_t stream) {
    const float* cart_coords = (const float*)d_in[0];
    const int*   species     = (const int*)d_in[1];
    // d_in[2] = batch_indices (unused: offsets derived from num_atoms in-kernel)
    const int*   num_atoms   = (const int*)d_in[3];
    const float* radii_table = (const float*)d_in[4];

    const int Bm = in_sizes[3];       // num_atoms is [B]

    float* penv = (float*)d_ws;       // B floats (16B-aligned base)
    float* out  = (float*)d_out;

    mol_kernel<<<(Bm + MPB - 1) / MPB, 256, 0, stream>>>(
        cart_coords, species, num_atoms, radii_table, penv, out, Bm);

    const int n4  = Bm / 4;
    const int rem = Bm - 4 * n4;
    reduce_kernel<<<1, 1024, 0, stream>>>((const float4*)penv, n4,
                                          penv + 4 * n4, rem, out, 1.0f / (float)Bm);
}